// Round 13
// baseline (3674.216 us; speedup 1.0000x reference)
//
#include <hip/hip_runtime.h>
#include <cstddef>
#include <cstdint>

// ---------------------------------------------------------------------------
// GRU seq2seq via MFMA. fp16 weights (single copy) x fp16 hi/lo-split acts.
// 32 clusters x 16 samples; 8 WGs/cluster (32 units each); WG = 8 waves.
// Round-13 (on r12's proven skeleton):
//  - 4-way accumulator rotation in phaseA/phaseB/shadow2/shadow1(w<6):
//    dependent-MFMA chains -> issue-bound (dep distance 4).
//  - epi_proj moved into bar2's shadow window (out-store off critical path).
//  - h_prev in registers (thread-private mapping), Hp LDS removed.
// Barrier: r10-proven MALL atomic add/poll, split arrive/wait with MFMA
// shadows. Dynamic XCD clustering via HW_REG_XCC_ID claim. h exchange:
// plain stores -> XCD L2 + sc0 staged loads.
// ---------------------------------------------------------------------------

typedef __attribute__((ext_vector_type(8))) _Float16 half8v;
typedef __attribute__((ext_vector_type(4))) float float4v;
typedef __attribute__((ext_vector_type(4))) unsigned uint4v;

static const size_t OFF_H0A = 0;                    // 512*256 (packed u32)
static const size_t OFF_H1A = 131072;
static const size_t OFF_H0B = 262144;
static const size_t OFF_H1B = 393216;
static const size_t OFF_WF  = 524288;               // 768*256
static const size_t OFF_BF  = OFF_WF + 196608;      // 768 (pad 1024)
static const size_t OFF_CTR = OFF_BF + 1024;        // 32*64 uints (MALL barrier)
static const size_t OFF_CLM = OFF_CTR + 2048;       // 8 uints (XCD claim), pad 64

#define SIGF(x) (1.0f / (1.0f + __expf(-(x))))
#define MFMA16F __builtin_amdgcn_mfma_f32_16x16x32_f16
#define MM2(C, W, BH, BL) \
    C = MFMA16F(W, BH, C, 0, 0, 0); \
    C = MFMA16F(W, BL, C, 0, 0, 0);
// dual-acc: hi-product -> C0, lo-product -> C1 (dep distance 2+)
#define MM2A(C0, C1, W, BH, BL) \
    C0 = MFMA16F(W, BH, C0, 0, 0, 0); \
    C1 = MFMA16F(W, BL, C1, 0, 0, 0);

__device__ __forceinline__ unsigned pack_h(float x) {
    _Float16 h = (_Float16)x;
    _Float16 l = (_Float16)(x - (float)h);
    unsigned short uh = __builtin_bit_cast(unsigned short, h);
    unsigned short ul = __builtin_bit_cast(unsigned short, l);
    return (unsigned)uh | ((unsigned)ul << 16);
}

// 32B sc0 load: bypass L1, read the XCD-shared L2 (fresh vs other CUs).
__device__ __forceinline__ void ld32_sc0(const void* p, uint4v& a, uint4v& b) {
    asm volatile("global_load_dwordx4 %0, %2, off sc0\n\t"
                 "global_load_dwordx4 %1, %2, off offset:16 sc0\n\t"
                 "s_waitcnt vmcnt(0)"
                 : "=v"(a), "=v"(b) : "v"(p) : "memory");
}

// Wf = dec_Wih0 @ outW ; bf = dec_Wih0 @ out_b + dec_bih0
__global__ void fuse_wb(const float* __restrict__ Wih0, const float* __restrict__ oW,
                        const float* __restrict__ ob, const float* __restrict__ bih0,
                        float* __restrict__ Wf, float* __restrict__ bf) {
    int idx = blockIdx.x * 256 + threadIdx.x;
    int r = idx >> 8, h = idx & 255;
    const float* wr = Wih0 + (size_t)r * 128;
    float a = 0.f;
    for (int k = 0; k < 128; ++k) a = fmaf(wr[k], oW[(size_t)k * 256 + h], a);
    Wf[idx] = a;
    if (h == 0) {
        float b = 0.f;
        for (int k = 0; k < 128; ++k) b = fmaf(wr[k], ob[k], b);
        bf[r] = b + bih0[r];
    }
}

__global__ __launch_bounds__(512, 1)
void behav_main(
    const float* __restrict__ pose,
    const float* __restrict__ eW0i, const float* __restrict__ eW0h,
    const float* __restrict__ eb0i, const float* __restrict__ eb0h,
    const float* __restrict__ eW1i, const float* __restrict__ eW1h,
    const float* __restrict__ eb1i, const float* __restrict__ eb1h,
    const float* __restrict__ dW0i, const float* __restrict__ dW0h,
    const float* __restrict__ db0i, const float* __restrict__ db0h,
    const float* __restrict__ dW1i, const float* __restrict__ dW1h,
    const float* __restrict__ db1i, const float* __restrict__ db1h,
    const float* __restrict__ oW, const float* __restrict__ ob,
    float* __restrict__ out,
    float* h0a, float* h0b, float* h1a, float* h1b,
    const float* __restrict__ Wf, const float* __restrict__ bf,
    unsigned* ctrs, unsigned* clm)
{
    // SLOT A: h1_prev. SLOT B: h0. fp16 hi/lo, chunk-XOR swizzled.
    __shared__ _Float16 Ah[16][256], Al[16][256], Bh[16][256], Bl[16][256]; // 32 KB
    __shared__ float Gt[28 * 288];     // [slot][row 16][col 16 pad 18] 31.5 KB
    __shared__ unsigned s_lin;
    // Gt slots: 0-5 p1 tiles (i-part when pre, else full) | 22,23 p1 n-h
    //   24-27 p1 rz-h (shadow2) | 6-17 p2 h-halves | 18,19 proj | 4,5,20,21 W2 n-i

    const int tid = threadIdx.x;
    const int lane = tid & 63;
    const int w = tid >> 6;

    // -------- dynamic XCD-local cluster formation (r10-proven) --------
    if (tid == 0) {
        unsigned xcc;
        asm volatile("s_getreg_b32 %0, hwreg(HW_REG_XCC_ID)" : "=s"(xcc));
        xcc &= 7u;
        unsigned pos = __hip_atomic_fetch_add(&clm[xcc], 1u,
                           __ATOMIC_RELAXED, __HIP_MEMORY_SCOPE_AGENT);
        s_lin = (xcc << 5) | (pos & 31u);
    }
    __syncthreads();
    const unsigned lin = s_lin;
    const int c = (int)(lin >> 3);              // xcc*4 + grp: XCD-tied
    const int uwg = (int)(lin & 7);
    const int s0 = c << 4, j0 = uwg << 5;
    unsigned* ctr = ctrs + (c << 6);            // MALL barrier counter
    unsigned epoch = 0;

    unsigned* h0pk[2] = { (unsigned*)h0a, (unsigned*)h0b };
    unsigned* h1pk[2] = { (unsigned*)h1a, (unsigned*)h1b };
    int pp = 0;

    const float4v FZ = {0.f, 0.f, 0.f, 0.f};
    const float obv = ((tid & 31) < 16) ? ob[(uwg << 4) + (tid & 31)] : 0.f;
    float hp0 = 0.f, hp1 = 0.f;                 // thread-private h_prev

    // MALL atomic barrier, split arrive/wait (mechanism r10-proven).
    auto arrive = [&]() {
        __syncthreads();
        ++epoch;
        if (tid == 0)
            __hip_atomic_fetch_add(ctr, 1u, __ATOMIC_RELAXED, __HIP_MEMORY_SCOPE_AGENT);
    };
    auto waitf = [&]() {
        if (tid == 0) {
            unsigned tgt = epoch * 8u;
            while (__hip_atomic_load(ctr, __ATOMIC_RELAXED, __HIP_MEMORY_SCOPE_AGENT) < tgt)
                __builtin_amdgcn_s_sleep(1);
        }
        __syncthreads();
    };

    // weight frag: lane holds W[row0+(lane&15)][col0+(lane>>4)*8 ..+7] as fp16
    auto ldfrag = [&](const float* M, int ldm, int row0, int col0, half8v& wv) {
        const float* p = M + (size_t)(row0 + (lane & 15)) * ldm + col0 + ((lane >> 4) << 3);
        float4 a = *(const float4*)p;
        float4 b = *(const float4*)(p + 4);
        float vv[8] = {a.x, a.y, a.z, a.w, b.x, b.y, b.z, b.w};
        #pragma unroll
        for (int i = 0; i < 8; ++i) wv[i] = (_Float16)vv[i];
    };
    auto rdS = [&](const _Float16 (*arr)[256], int kloc) -> half8v {
        int s = lane & 15, o = lane >> 4;
        int phys = ((kloc << 2) + o) ^ (s & 7);
        return *(const half8v*)&arr[s][phys << 3];
    };
    auto rdX = [&](int t, int loc, half8v& bh, half8v& bl) {
        const float* p = pose + (size_t)(s0 + (lane & 15)) * 8192 + (size_t)t * 128
                         + (loc << 5) + ((lane >> 4) << 3);
        float4 a = *(const float4*)p;
        float4 b = *(const float4*)(p + 4);
        float vv[8] = {a.x, a.y, a.z, a.w, b.x, b.y, b.z, b.w};
        #pragma unroll
        for (int i = 0; i < 8; ++i) {
            _Float16 h = (_Float16)vv[i];
            bh[i] = h;
            bl[i] = (_Float16)(vv[i] - (float)h);
        }
    };
    // stage packed h: 2 x dwordx4 sc0 loads (shared L2) -> swizzled LDS
    auto stage = [&](_Float16 (*ha)[256], _Float16 (*la)[256], const unsigned* src) {
        int s = tid >> 5, cc = tid & 31;
        uint4v a, b;
        ld32_sc0((const void*)(src + (size_t)(s0 + s) * 256 + (cc << 3)), a, b);
        unsigned u[8] = {a.x, a.y, a.z, a.w, b.x, b.y, b.z, b.w};
        half8v hv, lv;
        #pragma unroll
        for (int i = 0; i < 8; ++i) {
            hv[i] = __builtin_bit_cast(_Float16, (unsigned short)(u[i] & 0xFFFF));
            lv[i] = __builtin_bit_cast(_Float16, (unsigned short)(u[i] >> 16));
        }
        int phys = cc ^ (s & 7);
        *(half8v*)&ha[s][phys << 3] = hv;
        *(half8v*)&la[s][phys << 3] = lv;
    };
    auto gdump = [&](int slot, float4v a) {
        int col = lane & 15, ro = (lane >> 4) << 2;
        float* b = &Gt[slot * 288 + ro * 18 + col];
        b[0] = a.x; b[18] = a.y; b[36] = a.z; b[54] = a.w;
    };
    auto gtr = [&](int slot, int r16, int s) -> float {
        return Gt[slot * 288 + r16 * 18 + s];
    };

    // ---- register-stationary weights: <=28 frags/wave ----
    half8v WA[16], WB[8], WC[4];
    float b0r, b0z, b0ni, b0nh, b1r, b1z, b1ni, b1nh;

    auto load_era = [&](const float* W0i, bool x128, const float* W0h,
                        const float* W1i, const float* W1h) {
        if (w < 6) {
            const int rb1 = ((w >> 1) << 8) + j0 + ((w & 1) << 4);
            if (x128) {
                #pragma unroll
                for (int cc = 0; cc < 4; ++cc) ldfrag(W0i, 128, rb1, cc << 5, WA[cc]);
            } else {
                #pragma unroll
                for (int cc = 0; cc < 8; ++cc) ldfrag(W0i, 256, rb1, cc << 5, WA[cc]);
            }
            #pragma unroll
            for (int cc = 0; cc < 8; ++cc) ldfrag(W0h, 256, rb1, cc << 5, WA[8 + cc]);
            const int t2 = w >> 1;
            const int rb2 = ((t2 >> 1) << 8) + j0 + ((t2 & 1) << 4);
            const int kb = (w & 1) << 2;
            #pragma unroll
            for (int cc = 0; cc < 4; ++cc) ldfrag(W1h, 256, rb2, (kb + cc) << 5, WC[cc]);
            if (w < 4) {
                #pragma unroll
                for (int cc = 0; cc < 8; ++cc) ldfrag(W1i, 256, rb1, cc << 5, WB[cc]);
            } else {
                const int rb3 = 512 + j0 + ((w - 4) << 4);
                #pragma unroll
                for (int cc = 0; cc < 4; ++cc) ldfrag(W1i, 256, rb3, cc << 5, WB[cc]);
            }
        } else {
            #pragma unroll
            for (int j = 0; j < 3; ++j) {
                const int hh = 6 + (w - 6) * 3 + j;
                const int t2 = hh >> 1;
                const int rb2 = ((t2 >> 1) << 8) + j0 + ((t2 & 1) << 4);
                const int kb = (hh & 1) << 2;
                #pragma unroll
                for (int cc = 0; cc < 4; ++cc)
                    ldfrag(W1h, 256, rb2, (kb + cc) << 5, WA[4 * j + cc]);
            }
            #pragma unroll
            for (int cc = 0; cc < 4; ++cc)
                ldfrag(oW, 256, uwg << 4, (((w - 6) << 2) + cc) << 5, WA[12 + cc]);
            const int rb3 = 512 + j0 + ((w - 6) << 4);
            #pragma unroll
            for (int cc = 0; cc < 4; ++cc) ldfrag(W1i, 256, rb3, (4 + cc) << 5, WB[cc]);
        }
    };
    auto ldb0 = [&](const float* bi, const float* bhh) {
        int jj = j0 + (tid & 31);
        b0r = bi[jj] + bhh[jj]; b0z = bi[256 + jj] + bhh[256 + jj];
        b0ni = bi[512 + jj]; b0nh = bhh[512 + jj];
    };
    auto ldb1 = [&](const float* bi, const float* bhh) {
        int jj = j0 + (tid & 31);
        b1r = bi[jj] + bhh[jj]; b1z = bi[256 + jj] + bhh[256 + jj];
        b1ni = bi[512 + jj]; b1nh = bhh[512 + jj];
    };

    // ---- windows (split by dependency; 4-acc rotation) ----
    // Phase A: p1 i-part (Ah or X); + h-part (Bh) only when !pre.
    auto phaseA = [&](int t, bool xs, bool pre) {
        if (w >= 6) return;
        float4v a0 = FZ, a1 = FZ, a2 = FZ, a3 = FZ;
        if (xs) {
            #pragma unroll
            for (int cc = 0; cc < 4; ++cc) {
                half8v bh, bl; rdX(t, cc, bh, bl);
                if (cc & 1) { MM2A(a2, a3, WA[cc], bh, bl); }
                else        { MM2A(a0, a1, WA[cc], bh, bl); }
            }
        } else {
            #pragma unroll
            for (int cc = 0; cc < 8; ++cc) {
                half8v bh = rdS(Ah, cc), bl = rdS(Al, cc);
                if (cc & 1) { MM2A(a2, a3, WA[cc], bh, bl); }
                else        { MM2A(a0, a1, WA[cc], bh, bl); }
            }
        }
        if (!pre) {
            if (w < 4) {
                #pragma unroll
                for (int cc = 0; cc < 8; ++cc) {
                    half8v bh = rdS(Bh, cc), bl = rdS(Bl, cc);
                    if (cc & 1) { MM2A(a2, a3, WA[8 + cc], bh, bl); }
                    else        { MM2A(a0, a1, WA[8 + cc], bh, bl); }
                }
                gdump(w, a0 + a1 + a2 + a3);
            } else {
                float4v h0x = FZ, h1x = FZ, h2x = FZ, h3x = FZ;
                #pragma unroll
                for (int cc = 0; cc < 8; ++cc) {
                    half8v bh = rdS(Bh, cc), bl = rdS(Bl, cc);
                    if (cc & 1) { MM2A(h2x, h3x, WA[8 + cc], bh, bl); }
                    else        { MM2A(h0x, h1x, WA[8 + cc], bh, bl); }
                }
                gdump(w, a0 + a1 + a2 + a3);
                gdump(22 + (w - 4), h0x + h1x + h2x + h3x);
            }
        } else {
            gdump(w, a0 + a1 + a2 + a3);
        }
    };
    // Shadow2 (inside bar2 wait): NEXT step's p1 h-part from Bh (era-stable W0h).
    auto shadow2 = [&]() {
        if (w >= 6) return;
        float4v a0 = FZ, a1 = FZ, a2 = FZ, a3 = FZ;
        #pragma unroll
        for (int cc = 0; cc < 8; ++cc) {
            half8v bh = rdS(Bh, cc), bl = rdS(Bl, cc);
            if (cc & 1) { MM2A(a2, a3, WA[8 + cc], bh, bl); }
            else        { MM2A(a0, a1, WA[8 + cc], bh, bl); }
        }
        gdump((w < 4) ? (24 + w) : (22 + (w - 4)), a0 + a1 + a2 + a3);
    };
    // Shadow1 (inside bar1 wait): p2 h-halves + proj from Ah (= h1_prev).
    auto shadow1 = [&](bool pj) {
        if (w < 6) {
            float4v a0 = FZ, a1 = FZ, a2 = FZ, a3 = FZ;
            const int kb = (w & 1) << 2;
            #pragma unroll
            for (int cc = 0; cc < 4; ++cc) {
                half8v bh = rdS(Ah, kb + cc), bl = rdS(Al, kb + cc);
                if (cc & 1) { MM2A(a2, a3, WC[cc], bh, bl); }
                else        { MM2A(a0, a1, WC[cc], bh, bl); }
            }
            gdump(6 + w, a0 + a1 + a2 + a3);
        } else {
            float4v A0 = FZ, A1 = FZ, A2 = FZ, AJ = FZ;
            const bool w6 = (w == 6);
            #pragma unroll
            for (int cc = 0; cc < 4; ++cc) {      // chunks 0-3, read once
                half8v bh = rdS(Ah, cc), bl = rdS(Al, cc);
                if (w6) {
                    MM2(A0, WA[cc], bh, bl);
                    MM2(A2, WA[8 + cc], bh, bl);
                    if (pj) { MM2(AJ, WA[12 + cc], bh, bl); }
                } else {
                    MM2(A1, WA[4 + cc], bh, bl);
                }
            }
            #pragma unroll
            for (int cc = 0; cc < 4; ++cc) {      // chunks 4-7, read once
                half8v bh = rdS(Ah, 4 + cc), bl = rdS(Al, 4 + cc);
                if (w6) {
                    MM2(A1, WA[4 + cc], bh, bl);
                } else {
                    MM2(A0, WA[cc], bh, bl);
                    MM2(A2, WA[8 + cc], bh, bl);
                    if (pj) { MM2(AJ, WA[12 + cc], bh, bl); }
                }
            }
            const int base = 12 + (w - 6) * 3;
            gdump(base + 0, A0);
            gdump(base + 1, A1);
            gdump(base + 2, A2);
            if (pj) gdump(18 + (w - 6), AJ);
        }
    };
    // Phase B: p2 i-part from Bh (= h0_new).
    auto phaseB = [&]() {
        if (w < 4) {
            float4v a0 = FZ, a1 = FZ, a2 = FZ, a3 = FZ;
            #pragma unroll
            for (int cc = 0; cc < 8; ++cc) {
                half8v bh = rdS(Bh, cc), bl = rdS(Bl, cc);
                if (cc & 1) { MM2A(a2, a3, WB[cc], bh, bl); }
                else        { MM2A(a0, a1, WB[cc], bh, bl); }
            }
            gdump(w, a0 + a1 + a2 + a3);
        } else {
            float4v a0 = FZ, a1 = FZ;
            const int kb = (w >= 6) ? 4 : 0;
            #pragma unroll
            for (int cc = 0; cc < 4; ++cc) {
                half8v bh = rdS(Bh, kb + cc), bl = rdS(Bl, kb + cc);
                MM2A(a0, a1, WB[cc], bh, bl);
            }
            const int sl = (w == 4) ? 4 : (w == 5) ? 20 : (w == 6) ? 5 : 21;
            gdump(sl, a0 + a1);
        }
    };
    auto epi1 = [&](unsigned* pongpk, bool pre) {
        int s = tid >> 5, ul = tid & 31, t2 = ul >> 4, r16 = ul & 15;
        float gr = gtr(t2, r16, s);
        float gz = gtr(2 + t2, r16, s);
        if (pre) { gr += gtr(24 + t2, r16, s); gz += gtr(26 + t2, r16, s); }
        float r = SIGF(gr + b0r);
        float z = SIGF(gz + b0z);
        float n = tanhf(gtr(4 + t2, r16, s) + b0ni + r * (gtr(22 + t2, r16, s) + b0nh));
        float h = (1.f - z) * n + z * hp0;
        hp0 = h;
        pongpk[(size_t)(s0 + s) * 256 + j0 + ul] = pack_h(h);   // plain store -> L2
    };
    auto epi2 = [&](unsigned* pongpk) {
        int s = tid >> 5, ul = tid & 31, t2 = ul >> 4, r16 = ul & 15;
        float r = SIGF(gtr(t2, r16, s) + gtr(6 + (t2 << 1), r16, s)
                       + gtr(7 + (t2 << 1), r16, s) + b1r);
        float z = SIGF(gtr(2 + t2, r16, s) + gtr(10 + (t2 << 1), r16, s)
                       + gtr(11 + (t2 << 1), r16, s) + b1z);
        int nia = t2 ? 20 : 4, nib = t2 ? 21 : 5;
        float ni = gtr(nia, r16, s) + gtr(nib, r16, s);
        float nh = gtr(14 + (t2 << 1), r16, s) + gtr(15 + (t2 << 1), r16, s);
        float n = tanhf(ni + b1ni + r * (nh + b1nh));
        float h = (1.f - z) * n + z * hp1;
        hp1 = h;
        pongpk[(size_t)(s0 + s) * 256 + j0 + ul] = pack_h(h);   // plain store -> L2
    };
    auto epi_proj = [&](int tq) {
        int s = tid >> 5, ul = tid & 31;
        if (ul < 16) {
            float v = gtr(18, ul, s) + gtr(19, ul, s) + obv;
            out[(size_t)(s0 + s) * 65536 + (size_t)tq * 128 + (uwg << 4) + ul] = v;
        }
    };

    auto step = [&](int t, bool xs, bool pj, bool pre, bool sh2) {
        phaseA(t, xs, pre);
        __syncthreads();                    // sync1: Phase A dumps visible
        epi1(h0pk[pp ^ 1], pre);
        arrive();                           // bar1 arrive (h0_new L2-acked)
        shadow1(pj);                        //   Ah-dependent work in wait shadow
        waitf();                            // bar1 done (+ shadow1 dumps visible)
        stage(Bh, Bl, h0pk[pp ^ 1]);
        __syncthreads();                    // sync2: slot B = h0_new ready
        phaseB();
        __syncthreads();                    // sync3: Phase B dumps visible
        epi2(h1pk[pp ^ 1]);
        arrive();                           // bar2 arrive (h1_new L2-acked)
        if (pj) epi_proj(t - 1);            //   out-store in bar2 shadow
        if (sh2) shadow2();                 //   next-step Bh-dependent work
        waitf();                            // bar2 done
        stage(Ah, Al, h1pk[pp ^ 1]);
        __syncthreads();                    // sync4: slot A = h1_new ready
        pp ^= 1;
    };

    // ---- init ----
    {
        int s = tid >> 5, cc = tid & 31;
        half8v z;
        #pragma unroll
        for (int i = 0; i < 8; ++i) z[i] = (_Float16)0.f;
        *(half8v*)&Ah[s][cc << 3] = z;
        *(half8v*)&Al[s][cc << 3] = z;
        *(half8v*)&Bh[s][cc << 3] = z;
        *(half8v*)&Bl[s][cc << 3] = z;
    }
    __syncthreads();

    // ===================== ENCODER =====================
    load_era(eW0i, true, eW0h, eW1i, eW1h);
    ldb0(eb0i, eb0h); ldb1(eb1i, eb1h);
    for (int t = 0; t < 64; ++t) step(t, true, false, t > 0, t < 63);

    // ===================== DECODER =====================
    load_era(dW0i, true, dW0h, dW1i, dW1h);
    ldb0(db0i, db0h); ldb1(db1i, db1h);
    for (int t = 0; t < 512; ++t) {
        if (t == 64) {                      // AR era: only W0i-side changes
            if (w < 6) {
                const int rb1 = ((w >> 1) << 8) + j0 + ((w & 1) << 4);
                #pragma unroll
                for (int cc = 0; cc < 8; ++cc) ldfrag(Wf, 256, rb1, cc << 5, WA[cc]);
            }
            int jj = j0 + (tid & 31);
            b0r = bf[jj] + db0h[jj];
            b0z = bf[256 + jj] + db0h[256 + jj];
            b0ni = bf[512 + jj];
            b0nh = db0h[512 + jj];
        }
        step(t, t < 64, t >= 1, t > 0, t < 511);
    }

    // ===================== tail: out[511] = proj(h1_511) =====================
    if (w >= 6) {
        float4v accJ = FZ;
        const int cb = (w - 6) << 2;
        #pragma unroll
        for (int cc = 0; cc < 4; ++cc) {
            half8v bh = rdS(Ah, cb + cc), bl = rdS(Al, cb + cc);
            MM2(accJ, WA[12 + cc], bh, bl);
        }
        gdump(18 + (w - 6), accJ);
    }
    __syncthreads();
    epi_proj(511);
}

extern "C" void kernel_launch(void* const* d_in, const int* in_sizes, int n_in,
                              void* d_out, int out_size, void* d_ws, size_t ws_size,
                              hipStream_t stream) {
    (void)in_sizes; (void)n_in; (void)out_size; (void)ws_size;

    const float* pose = (const float*)d_in[0];
    const float* eW0i = (const float*)d_in[1];
    const float* eW0h = (const float*)d_in[2];
    const float* eb0i = (const float*)d_in[3];
    const float* eb0h = (const float*)d_in[4];
    const float* eW1i = (const float*)d_in[5];
    const float* eW1h = (const float*)d_in[6];
    const float* eb1i = (const float*)d_in[7];
    const float* eb1h = (const float*)d_in[8];
    const float* dW0i = (const float*)d_in[9];
    const float* dW0h = (const float*)d_in[10];
    const float* db0i = (const float*)d_in[11];
    const float* db0h = (const float*)d_in[12];
    const float* dW1i = (const float*)d_in[13];
    const float* dW1h = (const float*)d_in[14];
    const float* db1i = (const float*)d_in[15];
    const float* db1h = (const float*)d_in[16];
    const float* oW   = (const float*)d_in[17];
    const float* ob   = (const float*)d_in[18];

    float* ws = (float*)d_ws;
    float* h0a = ws + OFF_H0A;
    float* h0b = ws + OFF_H0B;
    float* h1a = ws + OFF_H1A;
    float* h1b = ws + OFF_H1B;
    float* Wf  = ws + OFF_WF;
    float* bf  = ws + OFF_BF;
    unsigned* ctrs = (unsigned*)(ws + OFF_CTR);
    unsigned* clm  = (unsigned*)(ws + OFF_CLM);
    float* outf = (float*)d_out;

    // zero MALL barrier counters + XCD claim counters (replayed in graph).
    hipMemsetAsync((void*)ctrs, 0, (2048 + 64) * sizeof(unsigned), stream);

    fuse_wb<<<dim3(768), dim3(256), 0, stream>>>(dW0i, oW, ob, db0i, Wf, bf);

    void* kargs[] = {
        (void*)&pose,
        (void*)&eW0i, (void*)&eW0h, (void*)&eb0i, (void*)&eb0h,
        (void*)&eW1i, (void*)&eW1h, (void*)&eb1i, (void*)&eb1h,
        (void*)&dW0i, (void*)&dW0h, (void*)&db0i, (void*)&db0h,
        (void*)&dW1i, (void*)&dW1h, (void*)&db1i, (void*)&db1h,
        (void*)&oW, (void*)&ob,
        (void*)&outf,
        (void*)&h0a, (void*)&h0b, (void*)&h1a, (void*)&h1b,
        (void*)&Wf, (void*)&bf,
        (void*)&ctrs, (void*)&clm
    };
    hipLaunchCooperativeKernel((const void*)behav_main, dim3(256), dim3(512),
                               kargs, 0, stream);
}

// Round 14
// 2849.063 us; speedup vs baseline: 1.2896x; 1.2896x over previous
//
#include <hip/hip_runtime.h>
#include <cstddef>
#include <cstdint>

// ---------------------------------------------------------------------------
// GRU seq2seq via MFMA. fp16 weights (single copy) x fp16 hi/lo-split acts.
// 32 clusters x 16 samples; 8 WGs/cluster (32 units each); WG = 8 waves.
// Round-14 = r12's proven structure (2667us) + two zero-register-cost moves:
//  - epi_proj in bar2's shadow window (out-store off the serial path).
//  - h_prev in registers (thread-private), Hp LDS removed.
// r13's 4-acc rotation REVERTED: it spilled accumulators to scratch
// (WRITE_SIZE 171->454MB, MfmaUtil 13.5->10). No AGPR headroom at
// 2 waves/SIMD with 28 resident weight frags.
// Barrier: r10-proven MALL atomic add/poll, split arrive/wait with MFMA
// shadows. Dynamic XCD clustering via HW_REG_XCC_ID claim. h exchange:
// plain stores -> XCD L2 + sc0 staged loads.
// ---------------------------------------------------------------------------

typedef __attribute__((ext_vector_type(8))) _Float16 half8v;
typedef __attribute__((ext_vector_type(4))) float float4v;
typedef __attribute__((ext_vector_type(4))) unsigned uint4v;

static const size_t OFF_H0A = 0;                    // 512*256 (packed u32)
static const size_t OFF_H1A = 131072;
static const size_t OFF_H0B = 262144;
static const size_t OFF_H1B = 393216;
static const size_t OFF_WF  = 524288;               // 768*256
static const size_t OFF_BF  = OFF_WF + 196608;      // 768 (pad 1024)
static const size_t OFF_CTR = OFF_BF + 1024;        // 32*64 uints (MALL barrier)
static const size_t OFF_CLM = OFF_CTR + 2048;       // 8 uints (XCD claim), pad 64

#define SIGF(x) (1.0f / (1.0f + __expf(-(x))))
#define MFMA16F __builtin_amdgcn_mfma_f32_16x16x32_f16
#define MM2(C, W, BH, BL) \
    C = MFMA16F(W, BH, C, 0, 0, 0); \
    C = MFMA16F(W, BL, C, 0, 0, 0);

__device__ __forceinline__ unsigned pack_h(float x) {
    _Float16 h = (_Float16)x;
    _Float16 l = (_Float16)(x - (float)h);
    unsigned short uh = __builtin_bit_cast(unsigned short, h);
    unsigned short ul = __builtin_bit_cast(unsigned short, l);
    return (unsigned)uh | ((unsigned)ul << 16);
}

// 32B sc0 load: bypass L1, read the XCD-shared L2 (fresh vs other CUs).
__device__ __forceinline__ void ld32_sc0(const void* p, uint4v& a, uint4v& b) {
    asm volatile("global_load_dwordx4 %0, %2, off sc0\n\t"
                 "global_load_dwordx4 %1, %2, off offset:16 sc0\n\t"
                 "s_waitcnt vmcnt(0)"
                 : "=v"(a), "=v"(b) : "v"(p) : "memory");
}

// Wf = dec_Wih0 @ outW ; bf = dec_Wih0 @ out_b + dec_bih0
__global__ void fuse_wb(const float* __restrict__ Wih0, const float* __restrict__ oW,
                        const float* __restrict__ ob, const float* __restrict__ bih0,
                        float* __restrict__ Wf, float* __restrict__ bf) {
    int idx = blockIdx.x * 256 + threadIdx.x;
    int r = idx >> 8, h = idx & 255;
    const float* wr = Wih0 + (size_t)r * 128;
    float a = 0.f;
    for (int k = 0; k < 128; ++k) a = fmaf(wr[k], oW[(size_t)k * 256 + h], a);
    Wf[idx] = a;
    if (h == 0) {
        float b = 0.f;
        for (int k = 0; k < 128; ++k) b = fmaf(wr[k], ob[k], b);
        bf[r] = b + bih0[r];
    }
}

__global__ __launch_bounds__(512, 1)
void behav_main(
    const float* __restrict__ pose,
    const float* __restrict__ eW0i, const float* __restrict__ eW0h,
    const float* __restrict__ eb0i, const float* __restrict__ eb0h,
    const float* __restrict__ eW1i, const float* __restrict__ eW1h,
    const float* __restrict__ eb1i, const float* __restrict__ eb1h,
    const float* __restrict__ dW0i, const float* __restrict__ dW0h,
    const float* __restrict__ db0i, const float* __restrict__ db0h,
    const float* __restrict__ dW1i, const float* __restrict__ dW1h,
    const float* __restrict__ db1i, const float* __restrict__ db1h,
    const float* __restrict__ oW, const float* __restrict__ ob,
    float* __restrict__ out,
    float* h0a, float* h0b, float* h1a, float* h1b,
    const float* __restrict__ Wf, const float* __restrict__ bf,
    unsigned* ctrs, unsigned* clm)
{
    // SLOT A: h1_prev. SLOT B: h0. fp16 hi/lo, chunk-XOR swizzled.
    __shared__ _Float16 Ah[16][256], Al[16][256], Bh[16][256], Bl[16][256]; // 32 KB
    __shared__ float Gt[28 * 288];     // [slot][row 16][col 16 pad 18] 31.5 KB
    __shared__ unsigned s_lin;
    // Gt slots: 0-5 p1 tiles (i-part when pre, else full) | 22,23 p1 n-h
    //   24-27 p1 rz-h (shadow2) | 6-17 p2 h-halves | 18,19 proj | 4,5,20,21 W2 n-i

    const int tid = threadIdx.x;
    const int lane = tid & 63;
    const int w = tid >> 6;

    // -------- dynamic XCD-local cluster formation (r10-proven) --------
    if (tid == 0) {
        unsigned xcc;
        asm volatile("s_getreg_b32 %0, hwreg(HW_REG_XCC_ID)" : "=s"(xcc));
        xcc &= 7u;
        unsigned pos = __hip_atomic_fetch_add(&clm[xcc], 1u,
                           __ATOMIC_RELAXED, __HIP_MEMORY_SCOPE_AGENT);
        s_lin = (xcc << 5) | (pos & 31u);
    }
    __syncthreads();
    const unsigned lin = s_lin;
    const int c = (int)(lin >> 3);              // xcc*4 + grp: XCD-tied
    const int uwg = (int)(lin & 7);
    const int s0 = c << 4, j0 = uwg << 5;
    unsigned* ctr = ctrs + (c << 6);            // MALL barrier counter
    unsigned epoch = 0;

    unsigned* h0pk[2] = { (unsigned*)h0a, (unsigned*)h0b };
    unsigned* h1pk[2] = { (unsigned*)h1a, (unsigned*)h1b };
    int pp = 0;

    const float4v FZ = {0.f, 0.f, 0.f, 0.f};
    const float obv = ((tid & 31) < 16) ? ob[(uwg << 4) + (tid & 31)] : 0.f;
    float hp0 = 0.f, hp1 = 0.f;                 // thread-private h_prev

    // MALL atomic barrier, split arrive/wait (mechanism r10-proven).
    auto arrive = [&]() {
        __syncthreads();
        ++epoch;
        if (tid == 0)
            __hip_atomic_fetch_add(ctr, 1u, __ATOMIC_RELAXED, __HIP_MEMORY_SCOPE_AGENT);
    };
    auto waitf = [&]() {
        if (tid == 0) {
            unsigned tgt = epoch * 8u;
            while (__hip_atomic_load(ctr, __ATOMIC_RELAXED, __HIP_MEMORY_SCOPE_AGENT) < tgt)
                __builtin_amdgcn_s_sleep(1);
        }
        __syncthreads();
    };

    // weight frag: lane holds W[row0+(lane&15)][col0+(lane>>4)*8 ..+7] as fp16
    auto ldfrag = [&](const float* M, int ldm, int row0, int col0, half8v& wv) {
        const float* p = M + (size_t)(row0 + (lane & 15)) * ldm + col0 + ((lane >> 4) << 3);
        float4 a = *(const float4*)p;
        float4 b = *(const float4*)(p + 4);
        float vv[8] = {a.x, a.y, a.z, a.w, b.x, b.y, b.z, b.w};
        #pragma unroll
        for (int i = 0; i < 8; ++i) wv[i] = (_Float16)vv[i];
    };
    auto rdS = [&](const _Float16 (*arr)[256], int kloc) -> half8v {
        int s = lane & 15, o = lane >> 4;
        int phys = ((kloc << 2) + o) ^ (s & 7);
        return *(const half8v*)&arr[s][phys << 3];
    };
    auto rdX = [&](int t, int loc, half8v& bh, half8v& bl) {
        const float* p = pose + (size_t)(s0 + (lane & 15)) * 8192 + (size_t)t * 128
                         + (loc << 5) + ((lane >> 4) << 3);
        float4 a = *(const float4*)p;
        float4 b = *(const float4*)(p + 4);
        float vv[8] = {a.x, a.y, a.z, a.w, b.x, b.y, b.z, b.w};
        #pragma unroll
        for (int i = 0; i < 8; ++i) {
            _Float16 h = (_Float16)vv[i];
            bh[i] = h;
            bl[i] = (_Float16)(vv[i] - (float)h);
        }
    };
    // stage packed h: 2 x dwordx4 sc0 loads (shared L2) -> swizzled LDS
    auto stage = [&](_Float16 (*ha)[256], _Float16 (*la)[256], const unsigned* src) {
        int s = tid >> 5, cc = tid & 31;
        uint4v a, b;
        ld32_sc0((const void*)(src + (size_t)(s0 + s) * 256 + (cc << 3)), a, b);
        unsigned u[8] = {a.x, a.y, a.z, a.w, b.x, b.y, b.z, b.w};
        half8v hv, lv;
        #pragma unroll
        for (int i = 0; i < 8; ++i) {
            hv[i] = __builtin_bit_cast(_Float16, (unsigned short)(u[i] & 0xFFFF));
            lv[i] = __builtin_bit_cast(_Float16, (unsigned short)(u[i] >> 16));
        }
        int phys = cc ^ (s & 7);
        *(half8v*)&ha[s][phys << 3] = hv;
        *(half8v*)&la[s][phys << 3] = lv;
    };
    auto gdump = [&](int slot, float4v a) {
        int col = lane & 15, ro = (lane >> 4) << 2;
        float* b = &Gt[slot * 288 + ro * 18 + col];
        b[0] = a.x; b[18] = a.y; b[36] = a.z; b[54] = a.w;
    };
    auto gtr = [&](int slot, int r16, int s) -> float {
        return Gt[slot * 288 + r16 * 18 + s];
    };

    // ---- register-stationary weights: <=28 frags/wave ----
    half8v WA[16], WB[8], WC[4];
    float b0r, b0z, b0ni, b0nh, b1r, b1z, b1ni, b1nh;

    auto load_era = [&](const float* W0i, bool x128, const float* W0h,
                        const float* W1i, const float* W1h) {
        if (w < 6) {
            const int rb1 = ((w >> 1) << 8) + j0 + ((w & 1) << 4);
            if (x128) {
                #pragma unroll
                for (int cc = 0; cc < 4; ++cc) ldfrag(W0i, 128, rb1, cc << 5, WA[cc]);
            } else {
                #pragma unroll
                for (int cc = 0; cc < 8; ++cc) ldfrag(W0i, 256, rb1, cc << 5, WA[cc]);
            }
            #pragma unroll
            for (int cc = 0; cc < 8; ++cc) ldfrag(W0h, 256, rb1, cc << 5, WA[8 + cc]);
            const int t2 = w >> 1;
            const int rb2 = ((t2 >> 1) << 8) + j0 + ((t2 & 1) << 4);
            const int kb = (w & 1) << 2;
            #pragma unroll
            for (int cc = 0; cc < 4; ++cc) ldfrag(W1h, 256, rb2, (kb + cc) << 5, WC[cc]);
            if (w < 4) {
                #pragma unroll
                for (int cc = 0; cc < 8; ++cc) ldfrag(W1i, 256, rb1, cc << 5, WB[cc]);
            } else {
                const int rb3 = 512 + j0 + ((w - 4) << 4);
                #pragma unroll
                for (int cc = 0; cc < 4; ++cc) ldfrag(W1i, 256, rb3, cc << 5, WB[cc]);
            }
        } else {
            #pragma unroll
            for (int j = 0; j < 3; ++j) {
                const int hh = 6 + (w - 6) * 3 + j;
                const int t2 = hh >> 1;
                const int rb2 = ((t2 >> 1) << 8) + j0 + ((t2 & 1) << 4);
                const int kb = (hh & 1) << 2;
                #pragma unroll
                for (int cc = 0; cc < 4; ++cc)
                    ldfrag(W1h, 256, rb2, (kb + cc) << 5, WA[4 * j + cc]);
            }
            #pragma unroll
            for (int cc = 0; cc < 4; ++cc)
                ldfrag(oW, 256, uwg << 4, (((w - 6) << 2) + cc) << 5, WA[12 + cc]);
            const int rb3 = 512 + j0 + ((w - 6) << 4);
            #pragma unroll
            for (int cc = 0; cc < 4; ++cc) ldfrag(W1i, 256, rb3, (4 + cc) << 5, WB[cc]);
        }
    };
    auto ldb0 = [&](const float* bi, const float* bhh) {
        int jj = j0 + (tid & 31);
        b0r = bi[jj] + bhh[jj]; b0z = bi[256 + jj] + bhh[256 + jj];
        b0ni = bi[512 + jj]; b0nh = bhh[512 + jj];
    };
    auto ldb1 = [&](const float* bi, const float* bhh) {
        int jj = j0 + (tid & 31);
        b1r = bi[jj] + bhh[jj]; b1z = bi[256 + jj] + bhh[256 + jj];
        b1ni = bi[512 + jj]; b1nh = bhh[512 + jj];
    };

    // ---- windows (split by dependency; r12 accumulator counts) ----
    // Phase A: p1 i-part (Ah or X); + h-part (Bh) only when !pre.
    auto phaseA = [&](int t, bool xs, bool pre) {
        if (w >= 6) return;
        float4v accI = FZ;
        if (xs) {
            #pragma unroll
            for (int cc = 0; cc < 4; ++cc) {
                half8v bh, bl; rdX(t, cc, bh, bl);
                MM2(accI, WA[cc], bh, bl);
            }
        } else {
            #pragma unroll
            for (int cc = 0; cc < 8; ++cc) {
                half8v bh = rdS(Ah, cc), bl = rdS(Al, cc);
                MM2(accI, WA[cc], bh, bl);
            }
        }
        if (!pre) {
            if (w < 4) {
                #pragma unroll
                for (int cc = 0; cc < 8; ++cc) {
                    half8v bh = rdS(Bh, cc), bl = rdS(Bl, cc);
                    MM2(accI, WA[8 + cc], bh, bl);
                }
                gdump(w, accI);
            } else {
                float4v accH = FZ;
                #pragma unroll
                for (int cc = 0; cc < 8; ++cc) {
                    half8v bh = rdS(Bh, cc), bl = rdS(Bl, cc);
                    MM2(accH, WA[8 + cc], bh, bl);
                }
                gdump(w, accI);
                gdump(22 + (w - 4), accH);
            }
        } else {
            gdump(w, accI);
        }
    };
    // Shadow2 (inside bar2 wait): NEXT step's p1 h-part from Bh (era-stable W0h).
    auto shadow2 = [&]() {
        if (w >= 6) return;
        float4v accH = FZ;
        #pragma unroll
        for (int cc = 0; cc < 8; ++cc) {
            half8v bh = rdS(Bh, cc), bl = rdS(Bl, cc);
            MM2(accH, WA[8 + cc], bh, bl);
        }
        gdump((w < 4) ? (24 + w) : (22 + (w - 4)), accH);
    };
    // Shadow1 (inside bar1 wait): p2 h-halves + proj from Ah (= h1_prev).
    auto shadow1 = [&](bool pj) {
        if (w < 6) {
            float4v accP = FZ;
            const int kb = (w & 1) << 2;
            #pragma unroll
            for (int cc = 0; cc < 4; ++cc) {
                half8v bh = rdS(Ah, kb + cc), bl = rdS(Al, kb + cc);
                MM2(accP, WC[cc], bh, bl);
            }
            gdump(6 + w, accP);
        } else {
            float4v A0 = FZ, A1 = FZ, A2 = FZ, AJ = FZ;
            const bool w6 = (w == 6);
            #pragma unroll
            for (int cc = 0; cc < 4; ++cc) {      // chunks 0-3, read once
                half8v bh = rdS(Ah, cc), bl = rdS(Al, cc);
                if (w6) {
                    MM2(A0, WA[cc], bh, bl);
                    MM2(A2, WA[8 + cc], bh, bl);
                    if (pj) { MM2(AJ, WA[12 + cc], bh, bl); }
                } else {
                    MM2(A1, WA[4 + cc], bh, bl);
                }
            }
            #pragma unroll
            for (int cc = 0; cc < 4; ++cc) {      // chunks 4-7, read once
                half8v bh = rdS(Ah, 4 + cc), bl = rdS(Al, 4 + cc);
                if (w6) {
                    MM2(A1, WA[4 + cc], bh, bl);
                } else {
                    MM2(A0, WA[cc], bh, bl);
                    MM2(A2, WA[8 + cc], bh, bl);
                    if (pj) { MM2(AJ, WA[12 + cc], bh, bl); }
                }
            }
            const int base = 12 + (w - 6) * 3;
            gdump(base + 0, A0);
            gdump(base + 1, A1);
            gdump(base + 2, A2);
            if (pj) gdump(18 + (w - 6), AJ);
        }
    };
    // Phase B: p2 i-part from Bh (= h0_new).
    auto phaseB = [&]() {
        if (w < 4) {
            float4v acc = FZ;
            #pragma unroll
            for (int cc = 0; cc < 8; ++cc) {
                half8v bh = rdS(Bh, cc), bl = rdS(Bl, cc);
                MM2(acc, WB[cc], bh, bl);
            }
            gdump(w, acc);
        } else {
            float4v acc = FZ;
            const int kb = (w >= 6) ? 4 : 0;
            #pragma unroll
            for (int cc = 0; cc < 4; ++cc) {
                half8v bh = rdS(Bh, kb + cc), bl = rdS(Bl, kb + cc);
                MM2(acc, WB[cc], bh, bl);
            }
            const int sl = (w == 4) ? 4 : (w == 5) ? 20 : (w == 6) ? 5 : 21;
            gdump(sl, acc);
        }
    };
    auto epi1 = [&](unsigned* pongpk, bool pre) {
        int s = tid >> 5, ul = tid & 31, t2 = ul >> 4, r16 = ul & 15;
        float gr = gtr(t2, r16, s);
        float gz = gtr(2 + t2, r16, s);
        if (pre) { gr += gtr(24 + t2, r16, s); gz += gtr(26 + t2, r16, s); }
        float r = SIGF(gr + b0r);
        float z = SIGF(gz + b0z);
        float n = tanhf(gtr(4 + t2, r16, s) + b0ni + r * (gtr(22 + t2, r16, s) + b0nh));
        float h = (1.f - z) * n + z * hp0;
        hp0 = h;
        pongpk[(size_t)(s0 + s) * 256 + j0 + ul] = pack_h(h);   // plain store -> L2
    };
    auto epi2 = [&](unsigned* pongpk) {
        int s = tid >> 5, ul = tid & 31, t2 = ul >> 4, r16 = ul & 15;
        float r = SIGF(gtr(t2, r16, s) + gtr(6 + (t2 << 1), r16, s)
                       + gtr(7 + (t2 << 1), r16, s) + b1r);
        float z = SIGF(gtr(2 + t2, r16, s) + gtr(10 + (t2 << 1), r16, s)
                       + gtr(11 + (t2 << 1), r16, s) + b1z);
        int nia = t2 ? 20 : 4, nib = t2 ? 21 : 5;
        float ni = gtr(nia, r16, s) + gtr(nib, r16, s);
        float nh = gtr(14 + (t2 << 1), r16, s) + gtr(15 + (t2 << 1), r16, s);
        float n = tanhf(ni + b1ni + r * (nh + b1nh));
        float h = (1.f - z) * n + z * hp1;
        hp1 = h;
        pongpk[(size_t)(s0 + s) * 256 + j0 + ul] = pack_h(h);   // plain store -> L2
    };
    auto epi_proj = [&](int tq) {
        int s = tid >> 5, ul = tid & 31;
        if (ul < 16) {
            float v = gtr(18, ul, s) + gtr(19, ul, s) + obv;
            out[(size_t)(s0 + s) * 65536 + (size_t)tq * 128 + (uwg << 4) + ul] = v;
        }
    };

    auto step = [&](int t, bool xs, bool pj, bool pre, bool sh2) {
        phaseA(t, xs, pre);
        __syncthreads();                    // sync1: Phase A dumps visible
        epi1(h0pk[pp ^ 1], pre);
        arrive();                           // bar1 arrive (h0_new L2-acked)
        shadow1(pj);                        //   Ah-dependent work in wait shadow
        waitf();                            // bar1 done (+ shadow1 dumps visible)
        stage(Bh, Bl, h0pk[pp ^ 1]);
        __syncthreads();                    // sync2: slot B = h0_new ready
        phaseB();
        __syncthreads();                    // sync3: Phase B dumps visible
        epi2(h1pk[pp ^ 1]);
        arrive();                           // bar2 arrive (h1_new L2-acked)
        if (pj) epi_proj(t - 1);            //   out-store in bar2 shadow
        if (sh2) shadow2();                 //   next-step Bh-dependent work
        waitf();                            // bar2 done
        stage(Ah, Al, h1pk[pp ^ 1]);
        __syncthreads();                    // sync4: slot A = h1_new ready
        pp ^= 1;
    };

    // ---- init ----
    {
        int s = tid >> 5, cc = tid & 31;
        half8v z;
        #pragma unroll
        for (int i = 0; i < 8; ++i) z[i] = (_Float16)0.f;
        *(half8v*)&Ah[s][cc << 3] = z;
        *(half8v*)&Al[s][cc << 3] = z;
        *(half8v*)&Bh[s][cc << 3] = z;
        *(half8v*)&Bl[s][cc << 3] = z;
    }
    __syncthreads();

    // ===================== ENCODER =====================
    load_era(eW0i, true, eW0h, eW1i, eW1h);
    ldb0(eb0i, eb0h); ldb1(eb1i, eb1h);
    for (int t = 0; t < 64; ++t) step(t, true, false, t > 0, t < 63);

    // ===================== DECODER =====================
    load_era(dW0i, true, dW0h, dW1i, dW1h);
    ldb0(db0i, db0h); ldb1(db1i, db1h);
    for (int t = 0; t < 512; ++t) {
        if (t == 64) {                      // AR era: only W0i-side changes
            if (w < 6) {
                const int rb1 = ((w >> 1) << 8) + j0 + ((w & 1) << 4);
                #pragma unroll
                for (int cc = 0; cc < 8; ++cc) ldfrag(Wf, 256, rb1, cc << 5, WA[cc]);
            }
            int jj = j0 + (tid & 31);
            b0r = bf[jj] + db0h[jj];
            b0z = bf[256 + jj] + db0h[256 + jj];
            b0ni = bf[512 + jj];
            b0nh = db0h[512 + jj];
        }
        step(t, t < 64, t >= 1, t > 0, t < 511);
    }

    // ===================== tail: out[511] = proj(h1_511) =====================
    if (w >= 6) {
        float4v accJ = FZ;
        const int cb = (w - 6) << 2;
        #pragma unroll
        for (int cc = 0; cc < 4; ++cc) {
            half8v bh = rdS(Ah, cb + cc), bl = rdS(Al, cb + cc);
            MM2(accJ, WA[12 + cc], bh, bl);
        }
        gdump(18 + (w - 6), accJ);
    }
    __syncthreads();
    epi_proj(511);
}

extern "C" void kernel_launch(void* const* d_in, const int* in_sizes, int n_in,
                              void* d_out, int out_size, void* d_ws, size_t ws_size,
                              hipStream_t stream) {
    (void)in_sizes; (void)n_in; (void)out_size; (void)ws_size;

    const float* pose = (const float*)d_in[0];
    const float* eW0i = (const float*)d_in[1];
    const float* eW0h = (const float*)d_in[2];
    const float* eb0i = (const float*)d_in[3];
    const float* eb0h = (const float*)d_in[4];
    const float* eW1i = (const float*)d_in[5];
    const float* eW1h = (const float*)d_in[6];
    const float* eb1i = (const float*)d_in[7];
    const float* eb1h = (const float*)d_in[8];
    const float* dW0i = (const float*)d_in[9];
    const float* dW0h = (const float*)d_in[10];
    const float* db0i = (const float*)d_in[11];
    const float* db0h = (const float*)d_in[12];
    const float* dW1i = (const float*)d_in[13];
    const float* dW1h = (const float*)d_in[14];
    const float* db1i = (const float*)d_in[15];
    const float* db1h = (const float*)d_in[16];
    const float* oW   = (const float*)d_in[17];
    const float* ob   = (const float*)d_in[18];

    float* ws = (float*)d_ws;
    float* h0a = ws + OFF_H0A;
    float* h0b = ws + OFF_H0B;
    float* h1a = ws + OFF_H1A;
    float* h1b = ws + OFF_H1B;
    float* Wf  = ws + OFF_WF;
    float* bf  = ws + OFF_BF;
    unsigned* ctrs = (unsigned*)(ws + OFF_CTR);
    unsigned* clm  = (unsigned*)(ws + OFF_CLM);
    float* outf = (float*)d_out;

    // zero MALL barrier counters + XCD claim counters (replayed in graph).
    hipMemsetAsync((void*)ctrs, 0, (2048 + 64) * sizeof(unsigned), stream);

    fuse_wb<<<dim3(768), dim3(256), 0, stream>>>(dW0i, oW, ob, db0i, Wf, bf);

    void* kargs[] = {
        (void*)&pose,
        (void*)&eW0i, (void*)&eW0h, (void*)&eb0i, (void*)&eb0h,
        (void*)&eW1i, (void*)&eW1h, (void*)&eb1i, (void*)&eb1h,
        (void*)&dW0i, (void*)&dW0h, (void*)&db0i, (void*)&db0h,
        (void*)&dW1i, (void*)&dW1h, (void*)&db1i, (void*)&db1h,
        (void*)&oW, (void*)&ob,
        (void*)&outf,
        (void*)&h0a, (void*)&h0b, (void*)&h1a, (void*)&h1b,
        (void*)&Wf, (void*)&bf,
        (void*)&ctrs, (void*)&clm
    };
    hipLaunchCooperativeKernel((const void*)behav_main, dim3(256), dim3(512),
                               kargs, 0, stream);
}

// Round 15
// 2537.244 us; speedup vs baseline: 1.4481x; 1.1229x over previous
//
#include <hip/hip_runtime.h>
#include <cstddef>
#include <cstdint>

// ---------------------------------------------------------------------------
// GRU seq2seq via MFMA. fp16 weights (single copy) x fp16 hi/lo-split acts.
// 32 clusters x 16 samples; 8 WGs/cluster (32 units each); WG = 8 waves.
// FINAL (= round-12 proven config, 2667us): r10 MALL atomic barrier with
// split arrive/wait + barrier-shadow MFMA:
//   shadow1 (inside bar1 wait): p2 h-halves + proj, depend only on Ah.
//   shadow2 (inside bar2 wait): next step's p1 h-part, depends only on Bh
//   (W0h era-stable). Serial path = 2/3 W1 + 1/3 W2 + 2 hidden barriers.
// Dynamic XCD clustering via s_getreg(HW_REG_XCC_ID) claim (r10-proven);
// h exchange: plain stores -> XCD L2, sc0 staged loads (r10-proven).
// r13/r14 variants (4-acc rotation, proj-in-shadow, h-in-regs) all measured
// slower or spilled; this is the empirical optimum of the lineage.
// ---------------------------------------------------------------------------

typedef __attribute__((ext_vector_type(8))) _Float16 half8v;
typedef __attribute__((ext_vector_type(4))) float float4v;
typedef __attribute__((ext_vector_type(4))) unsigned uint4v;

static const size_t OFF_H0A = 0;                    // 512*256 (packed u32)
static const size_t OFF_H1A = 131072;
static const size_t OFF_H0B = 262144;
static const size_t OFF_H1B = 393216;
static const size_t OFF_WF  = 524288;               // 768*256
static const size_t OFF_BF  = OFF_WF + 196608;      // 768 (pad 1024)
static const size_t OFF_CTR = OFF_BF + 1024;        // 32*64 uints (MALL barrier)
static const size_t OFF_CLM = OFF_CTR + 2048;       // 8 uints (XCD claim), pad 64

#define SIGF(x) (1.0f / (1.0f + __expf(-(x))))
#define MFMA16F __builtin_amdgcn_mfma_f32_16x16x32_f16
#define MM2(C, W, BH, BL) \
    C = MFMA16F(W, BH, C, 0, 0, 0); \
    C = MFMA16F(W, BL, C, 0, 0, 0);

__device__ __forceinline__ unsigned pack_h(float x) {
    _Float16 h = (_Float16)x;
    _Float16 l = (_Float16)(x - (float)h);
    unsigned short uh = __builtin_bit_cast(unsigned short, h);
    unsigned short ul = __builtin_bit_cast(unsigned short, l);
    return (unsigned)uh | ((unsigned)ul << 16);
}

// 32B sc0 load: bypass L1, read the XCD-shared L2 (fresh vs other CUs).
__device__ __forceinline__ void ld32_sc0(const void* p, uint4v& a, uint4v& b) {
    asm volatile("global_load_dwordx4 %0, %2, off sc0\n\t"
                 "global_load_dwordx4 %1, %2, off offset:16 sc0\n\t"
                 "s_waitcnt vmcnt(0)"
                 : "=v"(a), "=v"(b) : "v"(p) : "memory");
}

// Wf = dec_Wih0 @ outW ; bf = dec_Wih0 @ out_b + dec_bih0
__global__ void fuse_wb(const float* __restrict__ Wih0, const float* __restrict__ oW,
                        const float* __restrict__ ob, const float* __restrict__ bih0,
                        float* __restrict__ Wf, float* __restrict__ bf) {
    int idx = blockIdx.x * 256 + threadIdx.x;
    int r = idx >> 8, h = idx & 255;
    const float* wr = Wih0 + (size_t)r * 128;
    float a = 0.f;
    for (int k = 0; k < 128; ++k) a = fmaf(wr[k], oW[(size_t)k * 256 + h], a);
    Wf[idx] = a;
    if (h == 0) {
        float b = 0.f;
        for (int k = 0; k < 128; ++k) b = fmaf(wr[k], ob[k], b);
        bf[r] = b + bih0[r];
    }
}

__global__ __launch_bounds__(512, 1)
void behav_main(
    const float* __restrict__ pose,
    const float* __restrict__ eW0i, const float* __restrict__ eW0h,
    const float* __restrict__ eb0i, const float* __restrict__ eb0h,
    const float* __restrict__ eW1i, const float* __restrict__ eW1h,
    const float* __restrict__ eb1i, const float* __restrict__ eb1h,
    const float* __restrict__ dW0i, const float* __restrict__ dW0h,
    const float* __restrict__ db0i, const float* __restrict__ db0h,
    const float* __restrict__ dW1i, const float* __restrict__ dW1h,
    const float* __restrict__ db1i, const float* __restrict__ db1h,
    const float* __restrict__ oW, const float* __restrict__ ob,
    float* __restrict__ out,
    float* h0a, float* h0b, float* h1a, float* h1b,
    const float* __restrict__ Wf, const float* __restrict__ bf,
    unsigned* ctrs, unsigned* clm)
{
    // SLOT A: h1_prev. SLOT B: h0. fp16 hi/lo, chunk-XOR swizzled.
    __shared__ _Float16 Ah[16][256], Al[16][256], Bh[16][256], Bl[16][256]; // 32 KB
    __shared__ float Gt[28 * 288];     // [slot][row 16][col 16 pad 18] 31.5 KB
    __shared__ float Hp0[16][32], Hp1[16][32];                              // 4 KB
    __shared__ unsigned s_lin;
    // Gt slots: 0-5 p1 tiles (i-part when pre, else full) | 22,23 p1 n-h
    //   24-27 p1 rz-h (shadow2) | 6-17 p2 h-halves | 18,19 proj | 4,5,20,21 W2 n-i

    const int tid = threadIdx.x;
    const int lane = tid & 63;
    const int w = tid >> 6;

    // -------- dynamic XCD-local cluster formation (r10-proven) --------
    if (tid == 0) {
        unsigned xcc;
        asm volatile("s_getreg_b32 %0, hwreg(HW_REG_XCC_ID)" : "=s"(xcc));
        xcc &= 7u;
        unsigned pos = __hip_atomic_fetch_add(&clm[xcc], 1u,
                           __ATOMIC_RELAXED, __HIP_MEMORY_SCOPE_AGENT);
        s_lin = (xcc << 5) | (pos & 31u);
    }
    __syncthreads();
    const unsigned lin = s_lin;
    const int c = (int)(lin >> 3);              // xcc*4 + grp: XCD-tied
    const int uwg = (int)(lin & 7);
    const int s0 = c << 4, j0 = uwg << 5;
    unsigned* ctr = ctrs + (c << 6);            // MALL barrier counter
    unsigned epoch = 0;

    unsigned* h0pk[2] = { (unsigned*)h0a, (unsigned*)h0b };
    unsigned* h1pk[2] = { (unsigned*)h1a, (unsigned*)h1b };
    int pp = 0;

    const float4v FZ = {0.f, 0.f, 0.f, 0.f};
    const float obv = ((tid & 31) < 16) ? ob[(uwg << 4) + (tid & 31)] : 0.f;

    // MALL atomic barrier, split arrive/wait (mechanism r10-proven).
    // arrive: syncthreads drains vmcnt -> h plain-stores L2-acked, then +1.
    auto arrive = [&]() {
        __syncthreads();
        ++epoch;
        if (tid == 0)
            __hip_atomic_fetch_add(ctr, 1u, __ATOMIC_RELAXED, __HIP_MEMORY_SCOPE_AGENT);
    };
    auto waitf = [&]() {
        if (tid == 0) {
            unsigned tgt = epoch * 8u;
            while (__hip_atomic_load(ctr, __ATOMIC_RELAXED, __HIP_MEMORY_SCOPE_AGENT) < tgt)
                __builtin_amdgcn_s_sleep(1);
        }
        __syncthreads();
    };

    // weight frag: lane holds W[row0+(lane&15)][col0+(lane>>4)*8 ..+7] as fp16
    auto ldfrag = [&](const float* M, int ldm, int row0, int col0, half8v& wv) {
        const float* p = M + (size_t)(row0 + (lane & 15)) * ldm + col0 + ((lane >> 4) << 3);
        float4 a = *(const float4*)p;
        float4 b = *(const float4*)(p + 4);
        float vv[8] = {a.x, a.y, a.z, a.w, b.x, b.y, b.z, b.w};
        #pragma unroll
        for (int i = 0; i < 8; ++i) wv[i] = (_Float16)vv[i];
    };
    auto rdS = [&](const _Float16 (*arr)[256], int kloc) -> half8v {
        int s = lane & 15, o = lane >> 4;
        int phys = ((kloc << 2) + o) ^ (s & 7);
        return *(const half8v*)&arr[s][phys << 3];
    };
    auto rdX = [&](int t, int loc, half8v& bh, half8v& bl) {
        const float* p = pose + (size_t)(s0 + (lane & 15)) * 8192 + (size_t)t * 128
                         + (loc << 5) + ((lane >> 4) << 3);
        float4 a = *(const float4*)p;
        float4 b = *(const float4*)(p + 4);
        float vv[8] = {a.x, a.y, a.z, a.w, b.x, b.y, b.z, b.w};
        #pragma unroll
        for (int i = 0; i < 8; ++i) {
            _Float16 h = (_Float16)vv[i];
            bh[i] = h;
            bl[i] = (_Float16)(vv[i] - (float)h);
        }
    };
    // stage packed h: 2 x dwordx4 sc0 loads (shared L2) -> swizzled LDS
    auto stage = [&](_Float16 (*ha)[256], _Float16 (*la)[256], const unsigned* src) {
        int s = tid >> 5, cc = tid & 31;
        uint4v a, b;
        ld32_sc0((const void*)(src + (size_t)(s0 + s) * 256 + (cc << 3)), a, b);
        unsigned u[8] = {a.x, a.y, a.z, a.w, b.x, b.y, b.z, b.w};
        half8v hv, lv;
        #pragma unroll
        for (int i = 0; i < 8; ++i) {
            hv[i] = __builtin_bit_cast(_Float16, (unsigned short)(u[i] & 0xFFFF));
            lv[i] = __builtin_bit_cast(_Float16, (unsigned short)(u[i] >> 16));
        }
        int phys = cc ^ (s & 7);
        *(half8v*)&ha[s][phys << 3] = hv;
        *(half8v*)&la[s][phys << 3] = lv;
    };
    auto gdump = [&](int slot, float4v a) {
        int col = lane & 15, ro = (lane >> 4) << 2;
        float* b = &Gt[slot * 288 + ro * 18 + col];
        b[0] = a.x; b[18] = a.y; b[36] = a.z; b[54] = a.w;
    };
    auto gtr = [&](int slot, int r16, int s) -> float {
        return Gt[slot * 288 + r16 * 18 + s];
    };

    // ---- register-stationary weights: <=28 frags/wave ----
    half8v WA[16], WB[8], WC[4];
    float b0r, b0z, b0ni, b0nh, b1r, b1z, b1ni, b1nh;

    auto load_era = [&](const float* W0i, bool x128, const float* W0h,
                        const float* W1i, const float* W1h) {
        if (w < 6) {
            const int rb1 = ((w >> 1) << 8) + j0 + ((w & 1) << 4);
            if (x128) {
                #pragma unroll
                for (int cc = 0; cc < 4; ++cc) ldfrag(W0i, 128, rb1, cc << 5, WA[cc]);
            } else {
                #pragma unroll
                for (int cc = 0; cc < 8; ++cc) ldfrag(W0i, 256, rb1, cc << 5, WA[cc]);
            }
            #pragma unroll
            for (int cc = 0; cc < 8; ++cc) ldfrag(W0h, 256, rb1, cc << 5, WA[8 + cc]);
            const int t2 = w >> 1;
            const int rb2 = ((t2 >> 1) << 8) + j0 + ((t2 & 1) << 4);
            const int kb = (w & 1) << 2;
            #pragma unroll
            for (int cc = 0; cc < 4; ++cc) ldfrag(W1h, 256, rb2, (kb + cc) << 5, WC[cc]);
            if (w < 4) {
                #pragma unroll
                for (int cc = 0; cc < 8; ++cc) ldfrag(W1i, 256, rb1, cc << 5, WB[cc]);
            } else {
                const int rb3 = 512 + j0 + ((w - 4) << 4);
                #pragma unroll
                for (int cc = 0; cc < 4; ++cc) ldfrag(W1i, 256, rb3, cc << 5, WB[cc]);
            }
        } else {
            #pragma unroll
            for (int j = 0; j < 3; ++j) {
                const int hh = 6 + (w - 6) * 3 + j;
                const int t2 = hh >> 1;
                const int rb2 = ((t2 >> 1) << 8) + j0 + ((t2 & 1) << 4);
                const int kb = (hh & 1) << 2;
                #pragma unroll
                for (int cc = 0; cc < 4; ++cc)
                    ldfrag(W1h, 256, rb2, (kb + cc) << 5, WA[4 * j + cc]);
            }
            #pragma unroll
            for (int cc = 0; cc < 4; ++cc)
                ldfrag(oW, 256, uwg << 4, (((w - 6) << 2) + cc) << 5, WA[12 + cc]);
            const int rb3 = 512 + j0 + ((w - 6) << 4);
            #pragma unroll
            for (int cc = 0; cc < 4; ++cc) ldfrag(W1i, 256, rb3, (4 + cc) << 5, WB[cc]);
        }
    };
    auto ldb0 = [&](const float* bi, const float* bhh) {
        int jj = j0 + (tid & 31);
        b0r = bi[jj] + bhh[jj]; b0z = bi[256 + jj] + bhh[256 + jj];
        b0ni = bi[512 + jj]; b0nh = bhh[512 + jj];
    };
    auto ldb1 = [&](const float* bi, const float* bhh) {
        int jj = j0 + (tid & 31);
        b1r = bi[jj] + bhh[jj]; b1z = bi[256 + jj] + bhh[256 + jj];
        b1ni = bi[512 + jj]; b1nh = bhh[512 + jj];
    };

    // ---- windows (split by dependency) ----
    // Phase A: p1 i-part (Ah or X); + h-part (Bh) only when !pre.
    auto phaseA = [&](int t, bool xs, bool pre) {
        if (w >= 6) return;
        float4v accI = FZ;
        if (xs) {
            #pragma unroll
            for (int cc = 0; cc < 4; ++cc) {
                half8v bh, bl; rdX(t, cc, bh, bl);
                MM2(accI, WA[cc], bh, bl);
            }
        } else {
            #pragma unroll
            for (int cc = 0; cc < 8; ++cc) {
                half8v bh = rdS(Ah, cc), bl = rdS(Al, cc);
                MM2(accI, WA[cc], bh, bl);
            }
        }
        if (!pre) {
            if (w < 4) {
                #pragma unroll
                for (int cc = 0; cc < 8; ++cc) {
                    half8v bh = rdS(Bh, cc), bl = rdS(Bl, cc);
                    MM2(accI, WA[8 + cc], bh, bl);
                }
                gdump(w, accI);
            } else {
                float4v accH = FZ;
                #pragma unroll
                for (int cc = 0; cc < 8; ++cc) {
                    half8v bh = rdS(Bh, cc), bl = rdS(Bl, cc);
                    MM2(accH, WA[8 + cc], bh, bl);
                }
                gdump(w, accI);
                gdump(22 + (w - 4), accH);
            }
        } else {
            gdump(w, accI);
        }
    };
    // Shadow2 (inside bar2 wait): NEXT step's p1 h-part from Bh (era-stable W0h).
    auto shadow2 = [&]() {
        if (w >= 6) return;
        float4v accH = FZ;
        #pragma unroll
        for (int cc = 0; cc < 8; ++cc) {
            half8v bh = rdS(Bh, cc), bl = rdS(Bl, cc);
            MM2(accH, WA[8 + cc], bh, bl);
        }
        gdump((w < 4) ? (24 + w) : (22 + (w - 4)), accH);
    };
    // Shadow1 (inside bar1 wait): p2 h-halves + proj from Ah (= h1_prev).
    auto shadow1 = [&](bool pj) {
        if (w < 6) {
            float4v accP = FZ;
            const int kb = (w & 1) << 2;
            #pragma unroll
            for (int cc = 0; cc < 4; ++cc) {
                half8v bh = rdS(Ah, kb + cc), bl = rdS(Al, kb + cc);
                MM2(accP, WC[cc], bh, bl);
            }
            gdump(6 + w, accP);
        } else {
            float4v A0 = FZ, A1 = FZ, A2 = FZ, AJ = FZ;
            const bool w6 = (w == 6);
            #pragma unroll
            for (int cc = 0; cc < 4; ++cc) {      // chunks 0-3, read once
                half8v bh = rdS(Ah, cc), bl = rdS(Al, cc);
                if (w6) {
                    MM2(A0, WA[cc], bh, bl);
                    MM2(A2, WA[8 + cc], bh, bl);
                    if (pj) { MM2(AJ, WA[12 + cc], bh, bl); }
                } else {
                    MM2(A1, WA[4 + cc], bh, bl);
                }
            }
            #pragma unroll
            for (int cc = 0; cc < 4; ++cc) {      // chunks 4-7, read once
                half8v bh = rdS(Ah, 4 + cc), bl = rdS(Al, 4 + cc);
                if (w6) {
                    MM2(A1, WA[4 + cc], bh, bl);
                } else {
                    MM2(A0, WA[cc], bh, bl);
                    MM2(A2, WA[8 + cc], bh, bl);
                    if (pj) { MM2(AJ, WA[12 + cc], bh, bl); }
                }
            }
            const int base = 12 + (w - 6) * 3;
            gdump(base + 0, A0);
            gdump(base + 1, A1);
            gdump(base + 2, A2);
            if (pj) gdump(18 + (w - 6), AJ);
        }
    };
    // Phase B: p2 i-part from Bh (= h0_new).
    auto phaseB = [&]() {
        if (w < 4) {
            float4v acc = FZ;
            #pragma unroll
            for (int cc = 0; cc < 8; ++cc) {
                half8v bh = rdS(Bh, cc), bl = rdS(Bl, cc);
                MM2(acc, WB[cc], bh, bl);
            }
            gdump(w, acc);
        } else {
            float4v acc = FZ;
            const int kb = (w >= 6) ? 4 : 0;
            #pragma unroll
            for (int cc = 0; cc < 4; ++cc) {
                half8v bh = rdS(Bh, kb + cc), bl = rdS(Bl, kb + cc);
                MM2(acc, WB[cc], bh, bl);
            }
            const int sl = (w == 4) ? 4 : (w == 5) ? 20 : (w == 6) ? 5 : 21;
            gdump(sl, acc);
        }
    };
    auto epi1 = [&](unsigned* pongpk, bool pre) {
        int s = tid >> 5, ul = tid & 31, t2 = ul >> 4, r16 = ul & 15;
        float gr = gtr(t2, r16, s);
        float gz = gtr(2 + t2, r16, s);
        if (pre) { gr += gtr(24 + t2, r16, s); gz += gtr(26 + t2, r16, s); }
        float r = SIGF(gr + b0r);
        float z = SIGF(gz + b0z);
        float n = tanhf(gtr(4 + t2, r16, s) + b0ni + r * (gtr(22 + t2, r16, s) + b0nh));
        float h = (1.f - z) * n + z * Hp0[s][ul];
        Hp0[s][ul] = h;
        pongpk[(size_t)(s0 + s) * 256 + j0 + ul] = pack_h(h);   // plain store -> L2
    };
    auto epi2 = [&](unsigned* pongpk) {
        int s = tid >> 5, ul = tid & 31, t2 = ul >> 4, r16 = ul & 15;
        float r = SIGF(gtr(t2, r16, s) + gtr(6 + (t2 << 1), r16, s)
                       + gtr(7 + (t2 << 1), r16, s) + b1r);
        float z = SIGF(gtr(2 + t2, r16, s) + gtr(10 + (t2 << 1), r16, s)
                       + gtr(11 + (t2 << 1), r16, s) + b1z);
        int nia = t2 ? 20 : 4, nib = t2 ? 21 : 5;
        float ni = gtr(nia, r16, s) + gtr(nib, r16, s);
        float nh = gtr(14 + (t2 << 1), r16, s) + gtr(15 + (t2 << 1), r16, s);
        float n = tanhf(ni + b1ni + r * (nh + b1nh));
        float h = (1.f - z) * n + z * Hp1[s][ul];
        Hp1[s][ul] = h;
        pongpk[(size_t)(s0 + s) * 256 + j0 + ul] = pack_h(h);   // plain store -> L2
    };
    auto epi_proj = [&](int tq) {
        int s = tid >> 5, ul = tid & 31;
        if (ul < 16) {
            float v = gtr(18, ul, s) + gtr(19, ul, s) + obv;
            out[(size_t)(s0 + s) * 65536 + (size_t)tq * 128 + (uwg << 4) + ul] = v;
        }
    };

    auto step = [&](int t, bool xs, bool pj, bool pre, bool sh2) {
        phaseA(t, xs, pre);
        __syncthreads();                    // sync1: Phase A dumps visible
        epi1(h0pk[pp ^ 1], pre);
        arrive();                           // bar1 arrive (h0_new L2-acked)
        shadow1(pj);                        //   Ah-dependent work in wait shadow
        waitf();                            // bar1 done (+ shadow1 dumps visible)
        stage(Bh, Bl, h0pk[pp ^ 1]);
        if (pj) epi_proj(t - 1);            // drains under sync2 + phaseB
        __syncthreads();                    // sync2: slot B = h0_new ready
        phaseB();
        __syncthreads();                    // sync3: Phase B dumps visible
        epi2(h1pk[pp ^ 1]);
        arrive();                           // bar2 arrive (h1_new L2-acked)
        if (sh2) shadow2();                 //   next-step Bh-dependent work
        waitf();                            // bar2 done
        stage(Ah, Al, h1pk[pp ^ 1]);
        __syncthreads();                    // sync4: slot A = h1_new ready
        pp ^= 1;
    };

    // ---- init ----
    {
        int s = tid >> 5, cc = tid & 31;
        half8v z;
        #pragma unroll
        for (int i = 0; i < 8; ++i) z[i] = (_Float16)0.f;
        *(half8v*)&Ah[s][cc << 3] = z;
        *(half8v*)&Al[s][cc << 3] = z;
        *(half8v*)&Bh[s][cc << 3] = z;
        *(half8v*)&Bl[s][cc << 3] = z;
        Hp0[s][cc] = 0.f;
        Hp1[s][cc] = 0.f;
    }
    __syncthreads();

    // ===================== ENCODER =====================
    load_era(eW0i, true, eW0h, eW1i, eW1h);
    ldb0(eb0i, eb0h); ldb1(eb1i, eb1h);
    for (int t = 0; t < 64; ++t) step(t, true, false, t > 0, t < 63);

    // ===================== DECODER =====================
    load_era(dW0i, true, dW0h, dW1i, dW1h);
    ldb0(db0i, db0h); ldb1(db1i, db1h);
    for (int t = 0; t < 512; ++t) {
        if (t == 64) {                      // AR era: only W0i-side changes
            if (w < 6) {
                const int rb1 = ((w >> 1) << 8) + j0 + ((w & 1) << 4);
                #pragma unroll
                for (int cc = 0; cc < 8; ++cc) ldfrag(Wf, 256, rb1, cc << 5, WA[cc]);
            }
            int jj = j0 + (tid & 31);
            b0r = bf[jj] + db0h[jj];
            b0z = bf[256 + jj] + db0h[256 + jj];
            b0ni = bf[512 + jj];
            b0nh = db0h[512 + jj];
        }
        step(t, t < 64, t >= 1, t > 0, t < 511);
    }

    // ===================== tail: out[511] = proj(h1_511) =====================
    if (w >= 6) {
        float4v accJ = FZ;
        const int cb = (w - 6) << 2;
        #pragma unroll
        for (int cc = 0; cc < 4; ++cc) {
            half8v bh = rdS(Ah, cb + cc), bl = rdS(Al, cb + cc);
            MM2(accJ, WA[12 + cc], bh, bl);
        }
        gdump(18 + (w - 6), accJ);
    }
    __syncthreads();
    epi_proj(511);
}

extern "C" void kernel_launch(void* const* d_in, const int* in_sizes, int n_in,
                              void* d_out, int out_size, void* d_ws, size_t ws_size,
                              hipStream_t stream) {
    (void)in_sizes; (void)n_in; (void)out_size; (void)ws_size;

    const float* pose = (const float*)d_in[0];
    const float* eW0i = (const float*)d_in[1];
    const float* eW0h = (const float*)d_in[2];
    const float* eb0i = (const float*)d_in[3];
    const float* eb0h = (const float*)d_in[4];
    const float* eW1i = (const float*)d_in[5];
    const float* eW1h = (const float*)d_in[6];
    const float* eb1i = (const float*)d_in[7];
    const float* eb1h = (const float*)d_in[8];
    const float* dW0i = (const float*)d_in[9];
    const float* dW0h = (const float*)d_in[10];
    const float* db0i = (const float*)d_in[11];
    const float* db0h = (const float*)d_in[12];
    const float* dW1i = (const float*)d_in[13];
    const float* dW1h = (const float*)d_in[14];
    const float* db1i = (const float*)d_in[15];
    const float* db1h = (const float*)d_in[16];
    const float* oW   = (const float*)d_in[17];
    const float* ob   = (const float*)d_in[18];

    float* ws = (float*)d_ws;
    float* h0a = ws + OFF_H0A;
    float* h0b = ws + OFF_H0B;
    float* h1a = ws + OFF_H1A;
    float* h1b = ws + OFF_H1B;
    float* Wf  = ws + OFF_WF;
    float* bf  = ws + OFF_BF;
    unsigned* ctrs = (unsigned*)(ws + OFF_CTR);
    unsigned* clm  = (unsigned*)(ws + OFF_CLM);
    float* outf = (float*)d_out;

    // zero MALL barrier counters + XCD claim counters (replayed in graph).
    hipMemsetAsync((void*)ctrs, 0, (2048 + 64) * sizeof(unsigned), stream);

    fuse_wb<<<dim3(768), dim3(256), 0, stream>>>(dW0i, oW, ob, db0i, Wf, bf);

    void* kargs[] = {
        (void*)&pose,
        (void*)&eW0i, (void*)&eW0h, (void*)&eb0i, (void*)&eb0h,
        (void*)&eW1i, (void*)&eW1h, (void*)&eb1i, (void*)&eb1h,
        (void*)&dW0i, (void*)&dW0h, (void*)&db0i, (void*)&db0h,
        (void*)&dW1i, (void*)&dW1h, (void*)&db1i, (void*)&db1h,
        (void*)&oW, (void*)&ob,
        (void*)&outf,
        (void*)&h0a, (void*)&h0b, (void*)&h1a, (void*)&h1b,
        (void*)&Wf, (void*)&bf,
        (void*)&ctrs, (void*)&clm
    };
    hipLaunchCooperativeKernel((const void*)behav_main, dim3(256), dim3(512),
                               kargs, 0, stream);
}